// Round 14
// baseline (166.669 us; speedup 1.0000x reference)
//
#include <hip/hip_runtime.h>

// Problem constants
constexpr int kB  = 8;
constexpr int kT  = 2048;
constexpr int kG  = 1024;
constexpr int kNN = 600;
constexpr int kNE = 424;
constexpr int kD  = 1024;
constexpr int kL  = 2;
constexpr int kBNN = kB * kNN;   // 4800
constexpr int kBNE = kB * kNE;   // 3392
static_assert(kBNE % 64 == 0, "M tiles exact");

typedef __attribute__((ext_vector_type(4))) float f32x4;
typedef __attribute__((ext_vector_type(8))) short bf16x8;
typedef __attribute__((address_space(1))) const void gas_t;
typedef __attribute__((address_space(3))) void las_t;

__device__ __forceinline__ unsigned short f2bf(float x) {
    union { float f; unsigned u; } v; v.f = x;
    unsigned r = v.u + 0x7FFF + ((v.u >> 16) & 1);
    return (unsigned short)(r >> 16);
}

__device__ __forceinline__ void glds16(const void* g, void* l) {
    __builtin_amdgcn_global_load_lds((gas_t*)g, (las_t*)l, 16, 0, 0);
}

// out-tensor offsets for direct writes
__device__ __forceinline__ size_t edge_out_off(int row) {    // row in [0,kBNE)
    int b = row / kNE, r = row - b * kNE;
    return ((size_t)(b * kG + kNN + r)) * kD;
}
__device__ __forceinline__ size_t node_out_off(int n) {      // n in [0,kBNN)
    int b = n / kNN, g = n - b * kNN;
    return ((size_t)(b * kG + g)) * kD;
}

// ---------------------------------------------------------------------------
// prep kernel: block < kB*kG -> fused embedding gather + ragged mean pool;
// block >= kB*kG -> W [K][N] fp32 -> Wt in MFMA-FRAGMENT-LINEAR bf16 layout:
//   frag (nf,kf): lane l holds W[k = kf*32 + (l>>4)*8 + m][n = nf*16 + (l&15)],
//   1KB per fragment at offset ((nf*32)+kf)*1024 + l*16 (verified by element
//   trace: matches the mfma_f32_16x16x32_bf16 B-operand register image).
__global__ __launch_bounds__(256) void prep_kernel(const int* __restrict__ tokens,
                                                   const int* __restrict__ gids,
                                                   const float* __restrict__ emb,
                                                   float* __restrict__ nodes,
                                                   float* __restrict__ edges,
                                                   const float* __restrict__ Wm,
                                                   const float* __restrict__ Wu,
                                                   const float* __restrict__ We,
                                                   unsigned short* __restrict__ Wt) {
    __shared__ float tbuf[32][33];
    int bx = blockIdx.x;
    if (bx < kB * kG) {
        int b = bx >> 10, g = bx & (kG - 1);
        int d = threadIdx.x * 4;
        const int* row = gids + (size_t)b * kT;
        int lo = 0, hi = kT;
        while (lo < hi) { int m = (lo + hi) >> 1; if (row[m] < g) lo = m + 1; else hi = m; }
        int s = lo; hi = kT;
        while (lo < hi) { int m = (lo + hi) >> 1; if (row[m] <= g) lo = m + 1; else hi = m; }
        int e = lo;
        float4 acc = make_float4(0.f, 0.f, 0.f, 0.f);
        for (int t = s; t < e; ++t) {
            int tok = tokens[(size_t)b * kT + t];
            const float4 v = *(const float4*)(emb + (size_t)tok * kD + d);
            acc.x += v.x; acc.y += v.y; acc.z += v.z; acc.w += v.w;
        }
        int c = e - s;
        float sc = 1.0f / (float)(c > 0 ? c : 1);
        acc.x *= sc; acc.y *= sc; acc.z *= sc; acc.w *= sc;
        float* dstp = (g < kNN)
            ? (nodes + (size_t)(b * kNN + g) * kD + d)
            : (edges + (size_t)(b * kNE + (g - kNN)) * kD + d);
        *(float4*)dstp = acc;
    } else {
        int idx = bx - kB * kG;             // [0, 6*1024)
        int z = idx >> 10;
        int rem = idx & 1023;
        int n0 = (rem & 31) * 32, k0 = (rem >> 5) * 32;
        const float* W = (z < 2) ? (Wm + (size_t)z * kD * kD)
                       : (z < 4) ? (Wu + (size_t)(z - 2) * kD * kD)
                                 : (We + (size_t)(z - 4) * kD * kD);
        int r = threadIdx.x >> 3, c4 = (threadIdx.x & 7) * 4;
        const float4 v = *(const float4*)(W + (size_t)(k0 + r) * kD + n0 + c4);
        tbuf[r][c4] = v.x; tbuf[r][c4 + 1] = v.y; tbuf[r][c4 + 2] = v.z; tbuf[r][c4 + 3] = v.w;
        __syncthreads();
        if (threadIdx.x < 128) {
            int f = threadIdx.x >> 6, l = threadIdx.x & 63;
            alignas(16) unsigned short tmp[8];
#pragma unroll
            for (int m = 0; m < 8; ++m)
                tmp[m] = f2bf(tbuf[(l >> 4) * 8 + m][f * 16 + (l & 15)]);
            int nf = (rem & 31) * 2 + f;    // n0/16 + f
            int kf = rem >> 5;              // k0/32
            char* dst = (char*)Wt + (size_t)z * 2097152
                      + ((size_t)nf * 32 + kf) * 1024 + (size_t)l * 16;
            *(float4*)dst = *(const float4*)tmp;
        }
    }
}

// ---------------------------------------------------------------------------
// gather (+ optional node->out copy folded in, for L1)
template <int COPY>
__global__ void gather_kernel(const float* __restrict__ nodes,
                              const float* __restrict__ edges,
                              const int* __restrict__ src,
                              const int* __restrict__ dst,
                              unsigned short* __restrict__ bufM,
                              unsigned short* __restrict__ bufE,
                              float* __restrict__ out) {
    int d = threadIdx.x * 4;
    int e = blockIdx.x;
    if (COPY && e >= kBNE) {
        int n = e - kBNE;
        *(float4*)(out + node_out_off(n) + d) =
            *(const float4*)(nodes + (size_t)n * kD + d);
        return;
    }
    int s = src[e], t = dst[e];
    const float4 a = *(const float4*)(nodes + (size_t)s * kD + d);
    const float4 b = *(const float4*)(edges + (size_t)e * kD + d);
    const float4 c = *(const float4*)(nodes + (size_t)t * kD + d);
    ushort4 om, oe;
    om.x = f2bf(a.x + b.x); om.y = f2bf(a.y + b.y);
    om.z = f2bf(a.z + b.z); om.w = f2bf(a.w + b.w);
    oe.x = f2bf(a.x + c.x); oe.y = f2bf(a.y + c.y);
    oe.z = f2bf(a.z + c.z); oe.w = f2bf(a.w + c.w);
    *(ushort4*)(bufM + (size_t)e * kD + d) = om;
    *(ushort4*)(bufE + (size_t)e * kD + d) = oe;
}

// ---------------------------------------------------------------------------
// bf16 MFMA GEMM core. A [M][1024] bf16; Wtf = fragment-linear weights.
// 64x128 tile, BK=64, 4 waves (2x2 over 32x64 sub-tiles), 16x16x32 MFMA.
// A: LDS 3-buffer ring (8KB/buf), r12's XOR chunk layout (2 glds/thread/stage).
// B: NO LDS — per-wave coalesced 1KB global loads of pre-packed fragments,
//    register double-buffered one K-step ahead (bfr[2] ping-pong, unrolled ph).
// ORDER-PINNED counted vmcnt (fix for r13's NaN): empty memory-clobber asm
// fences between stage / loadB / ds_read groups force VMEM FIFO order ==
// program order, making the counted waits deterministic:
//   t=0: vmcnt(10)  [retires stage(0); leaves stage(1)+loadB(0)]
//   steady: vmcnt(18) [after stage(t): B(t-1)8 + s(t+1)2 + B(t)8 = 18]
//   last: vmcnt(16)   [after stage(nt-1): B(nt-2)8 + B(nt-1)8]
// sched_barrier(0) after each wait blocks MFMA/ds hoisting (rule #18).
// MODE 0: Cb[row][col] = bf16(relu(acc))                     (msg GEMM)
// MODE 1: Cf[row][col] += acc          (edge GEMM L0; unique rows)
// MODE 2: Of[edge_out_off(row)+col] = Ef[row][col] + acc     (edge GEMM L1)
// MODE 3: atomicAdd(Cf[idxp[row]][col], acc)                 (update L0)
// MODE 4: atomicAdd(Of[node_out_off(idxp[row])+col], acc)    (update L1)
template <int MODE>
__device__ __forceinline__ void gemm_body(const unsigned short* __restrict__ A,
                                          const unsigned short* __restrict__ Wtf,
                                          float* __restrict__ Cf,
                                          unsigned short* __restrict__ Cb,
                                          const float* __restrict__ Ef,
                                          const int* __restrict__ idxp,
                                          char* smem, int bn, int bm) {
    const int tid = threadIdx.x;
    const int lane = tid & 63;
    const int w = tid >> 6;
    const int wr = w >> 1, wc = w & 1;
    const int row0 = bm * 64, col0 = bn * 128;
    const int l15 = lane & 15, kg = lane >> 4;

    // ---- A staging (r12 scheme): lane l covers slab-row (l>>3), chunk-pos
    // (l&7); source chunk = (l&7) ^ (l>>3).
    const int sl8 = lane >> 3;
    const int sc  = (lane & 7) ^ sl8;
    const unsigned short* agp[2];
#pragma unroll
    for (int q = 0; q < 2; ++q)
        agp[q] = A + (size_t)(row0 + (w * 2 + q) * 8 + sl8) * kD + sc * 8;
    auto stage = [&](int bsel, int k0) {
        char* base = smem + bsel * 8192;
#pragma unroll
        for (int q = 0; q < 2; ++q)
            glds16(agp[q] + k0, base + (w * 2 + q) * 1024);
    };

    // ---- B fragment pointers: this wave reads frags nf = bn*8 + wc*4 + j.
    const char* bfrag[4];
#pragma unroll
    for (int j = 0; j < 4; ++j)
        bfrag[j] = (const char*)Wtf
                 + ((size_t)(bn * 8 + wc * 4 + j) * 32) * 1024 + (size_t)lane * 16;

    constexpr int nt = kD / 64;                 // 16 (even)
    bf16x8 bfr[2][2][4];                        // [ping][kk][j]

    stage(0, 0);
    stage(1, 64);
    asm volatile("" ::: "memory");              // pin: stages before B loads
#pragma unroll
    for (int kk = 0; kk < 2; ++kk)
#pragma unroll
        for (int j = 0; j < 4; ++j)
            bfr[0][kk][j] = *(const bf16x8*)(bfrag[j] + (size_t)kk * 1024);

    f32x4 acc[2][4] = {};
    for (int tt = 0; tt < nt; tt += 2) {
#pragma unroll
        for (int ph = 0; ph < 2; ++ph) {        // ph compile-time after unroll
            const int t = tt + ph;
            char* bufc = smem + (t % 3) * 8192;
            if (t == 0)          asm volatile("s_waitcnt vmcnt(10)" ::: "memory");
            else if (t < nt - 1) asm volatile("s_waitcnt vmcnt(18)" ::: "memory");
            else                 asm volatile("s_waitcnt vmcnt(16)" ::: "memory");
            __builtin_amdgcn_sched_barrier(0);
            __builtin_amdgcn_s_barrier();       // A buf[t%3] staged for all waves
            if (t + 2 < nt) stage((t + 2) % 3, (t + 2) * 64);
            asm volatile("" ::: "memory");      // pin: stage before loadB
            if (t + 1 < nt) {
#pragma unroll
                for (int kk = 0; kk < 2; ++kk)
#pragma unroll
                    for (int j = 0; j < 4; ++j)
                        bfr[ph ^ 1][kk][j] = *(const bf16x8*)(
                            bfrag[j] + (size_t)((t + 1) * 2 + kk) * 1024);
            }
            asm volatile("" ::: "memory");      // pin: loadB before ds_reads
            bf16x8 af[2][2];
#pragma unroll
            for (int kk = 0; kk < 2; ++kk)
#pragma unroll
                for (int i = 0; i < 2; ++i) {
                    int ar = wr * 32 + i * 16 + l15;
                    int p = ((kk << 2) | kg) ^ (ar & 7);
                    af[kk][i] = *(const bf16x8*)(bufc + ar * 128 + p * 16);
                }
            asm volatile("s_waitcnt lgkmcnt(0)" ::: "memory");  // A reads landed
            __builtin_amdgcn_sched_barrier(0);
#pragma unroll
            for (int kk = 0; kk < 2; ++kk)
#pragma unroll
                for (int i = 0; i < 2; ++i)
#pragma unroll
                    for (int j = 0; j < 4; ++j)
                        acc[i][j] = __builtin_amdgcn_mfma_f32_16x16x32_bf16(
                            af[kk][i], bfr[ph][kk][j], acc[i][j], 0, 0, 0);
        }
    }

    // epilogue: C/D layout col=lane&15, row=(lane>>4)*4+reg
    const int lr = (lane >> 4) * 4;
#pragma unroll
    for (int i = 0; i < 2; ++i) {
        int rbase = row0 + wr * 32 + i * 16 + lr;
#pragma unroll
        for (int r = 0; r < 4; ++r) {
            int row = rbase + r;
            if (MODE == 0) {
                unsigned short* cp = Cb + (size_t)row * kD;
#pragma unroll
                for (int j = 0; j < 4; ++j) {
                    int col = col0 + wc * 64 + j * 16 + l15;
                    cp[col] = f2bf(fmaxf(acc[i][j][r], 0.f));
                }
            } else if (MODE == 1) {
                float* cp = Cf + (size_t)row * kD;
#pragma unroll
                for (int j = 0; j < 4; ++j) {
                    int col = col0 + wc * 64 + j * 16 + l15;
                    cp[col] += acc[i][j][r];
                }
            } else if (MODE == 2) {
                const float* ep = Ef + (size_t)row * kD;
                float* op = Cf + edge_out_off(row);
#pragma unroll
                for (int j = 0; j < 4; ++j) {
                    int col = col0 + wc * 64 + j * 16 + l15;
                    op[col] = ep[col] + acc[i][j][r];
                }
            } else if (MODE == 3) {
                float* cp = Cf + (size_t)idxp[row] * kD;
#pragma unroll
                for (int j = 0; j < 4; ++j) {
                    int col = col0 + wc * 64 + j * 16 + l15;
                    atomicAdd(cp + col, acc[i][j][r]);
                }
            } else {
                float* cp = Cf + node_out_off(idxp[row]);
#pragma unroll
                for (int j = 0; j < 4; ++j) {
                    int col = col0 + wc * 64 + j * 16 + l15;
                    atomicAdd(cp + col, acc[i][j][r]);
                }
            }
        }
    }
}

// L0: z=0 msgb = bf16(relu(bufM @ WtM^T));  z=1 edges += bufE @ WtE^T
__global__ __launch_bounds__(256) void gemm_dual_l0(const unsigned short* __restrict__ A0,
                                                    const unsigned short* __restrict__ B0,
                                                    unsigned short* __restrict__ C0,
                                                    const unsigned short* __restrict__ A1,
                                                    const unsigned short* __restrict__ B1,
                                                    float* __restrict__ C1) {
    __shared__ char smem[24576];
    if (blockIdx.z == 0)
        gemm_body<0>(A0, B0, nullptr, C0, nullptr, nullptr, smem, blockIdx.x, blockIdx.y);
    else
        gemm_body<1>(A1, B1, C1, nullptr, nullptr, nullptr, smem, blockIdx.x, blockIdx.y);
}

// L1: z=0 msgb = bf16(relu(bufM @ WtM^T));  z=1 out_edges = edges + bufE @ WtE^T
__global__ __launch_bounds__(256) void gemm_dual_l1(const unsigned short* __restrict__ A0,
                                                    const unsigned short* __restrict__ B0,
                                                    unsigned short* __restrict__ C0,
                                                    const unsigned short* __restrict__ A1,
                                                    const unsigned short* __restrict__ B1,
                                                    float* __restrict__ outp,
                                                    const float* __restrict__ edges) {
    __shared__ char smem[24576];
    if (blockIdx.z == 0)
        gemm_body<0>(A0, B0, nullptr, C0, nullptr, nullptr, smem, blockIdx.x, blockIdx.y);
    else
        gemm_body<2>(A1, B1, outp, nullptr, edges, nullptr, smem, blockIdx.x, blockIdx.y);
}

// nodes[dst[row]] += (msgb @ WtU^T)[row]   (full K, one atomic per element)
__global__ __launch_bounds__(256) void gemm_upd_l0(const unsigned short* __restrict__ A,
                                                   const unsigned short* __restrict__ B,
                                                   float* __restrict__ C,
                                                   const int* __restrict__ dstIdx) {
    __shared__ char smem[24576];
    gemm_body<3>(A, B, C, nullptr, nullptr, dstIdx, smem, blockIdx.x, blockIdx.y);
}

// out_nodes[dst[row]] += (msgb @ WtU^T)[row]  (final layer -> d_out directly)
__global__ __launch_bounds__(256) void gemm_upd_l1(const unsigned short* __restrict__ A,
                                                   const unsigned short* __restrict__ B,
                                                   float* __restrict__ outp,
                                                   const int* __restrict__ dstIdx) {
    __shared__ char smem[24576];
    gemm_body<4>(A, B, outp, nullptr, nullptr, dstIdx, smem, blockIdx.x, blockIdx.y);
}

// ---------------------------------------------------------------------------
extern "C" void kernel_launch(void* const* d_in, const int* in_sizes, int n_in,
                              void* d_out, int out_size, void* d_ws, size_t ws_size,
                              hipStream_t stream) {
    const int*   tokens = (const int*)d_in[0];
    const int*   gids   = (const int*)d_in[1];
    const int*   eidx   = (const int*)d_in[3];
    const float* emb    = (const float*)d_in[4];
    const float* Wm     = (const float*)d_in[5];
    const float* Wu     = (const float*)d_in[6];
    const float* We     = (const float*)d_in[7];
    float* out = (float*)d_out;

    // workspace layout
    constexpr size_t szNodes = (size_t)kBNN * kD * 4;   // fp32 master
    constexpr size_t szEdges = (size_t)kBNE * kD * 4;   // fp32 master
    constexpr size_t szBufM  = (size_t)kBNE * kD * 2;   // bf16
    constexpr size_t szBufE  = (size_t)kBNE * kD * 2;   // bf16
    constexpr size_t szMsgB  = (size_t)kBNE * kD * 2;   // bf16
    char* ws = (char*)d_ws;
    float*          nodes = (float*)ws;
    float*          edges = (float*)(ws + szNodes);
    unsigned short* bufM  = (unsigned short*)(ws + szNodes + szEdges);
    unsigned short* bufE  = (unsigned short*)(ws + szNodes + szEdges + szBufM);
    unsigned short* msgb  = (unsigned short*)(ws + szNodes + szEdges + szBufM + szBufE);
    unsigned short* Wt    = (unsigned short*)(ws + szNodes + szEdges + szBufM + szBufE + szMsgB);

    const int* srcIdx = eidx;
    const int* dstIdx = eidx + kBNE;
    unsigned short* WtM = Wt;                           // frag-linear, 2MB each
    unsigned short* WtU = Wt + (size_t)2 * kD * kD;
    unsigned short* WtE = Wt + (size_t)4 * kD * kD;

    // pool (binary-search bounds) + weight frag-pack, one launch
    prep_kernel<<<kB * kG + 6 * 1024, 256, 0, stream>>>(
        tokens, gids, emb, nodes, edges, Wm, Wu, We, Wt);

    constexpr int mt = kBNE / 64;                // 53
    const dim3 gdual(kD / 128, mt, 2);           // 848 blocks
    const dim3 gupd(kD / 128, mt, 1);            // 424 blocks, full K

    // ---- layer 0 ----
    gather_kernel<0><<<kBNE, 256, 0, stream>>>(nodes, edges, srcIdx, dstIdx, bufM, bufE, out);
    gemm_dual_l0<<<gdual, 256, 0, stream>>>(bufM, WtM, msgb, bufE, WtE, edges);
    gemm_upd_l0<<<gupd, 256, 0, stream>>>(msgb, WtU, nodes, dstIdx);

    // ---- layer 1 (writes final values straight into d_out) ----
    gather_kernel<1><<<kBNE + kBNN, 256, 0, stream>>>(nodes, edges, srcIdx, dstIdx, bufM, bufE, out);
    gemm_dual_l1<<<gdual, 256, 0, stream>>>(bufM, WtM + (size_t)kD * kD, msgb,
                                            bufE, WtE + (size_t)kD * kD, out, edges);
    gemm_upd_l1<<<gupd, 256, 0, stream>>>(msgb, WtU + (size_t)kD * kD, out, dstIdx);
}

// Round 15
// 164.929 us; speedup vs baseline: 1.0106x; 1.0106x over previous
//
#include <hip/hip_runtime.h>

// Problem constants
constexpr int kB  = 8;
constexpr int kT  = 2048;
constexpr int kG  = 1024;
constexpr int kNN = 600;
constexpr int kNE = 424;
constexpr int kD  = 1024;
constexpr int kL  = 2;
constexpr int kBNN = kB * kNN;   // 4800
constexpr int kBNE = kB * kNE;   // 3392
static_assert(kBNE % 64 == 0, "M tiles exact");

typedef __attribute__((ext_vector_type(4))) float f32x4;
typedef __attribute__((ext_vector_type(8))) short bf16x8;
typedef __attribute__((address_space(1))) const void gas_t;
typedef __attribute__((address_space(3))) void las_t;

__device__ __forceinline__ unsigned short f2bf(float x) {
    union { float f; unsigned u; } v; v.f = x;
    unsigned r = v.u + 0x7FFF + ((v.u >> 16) & 1);
    return (unsigned short)(r >> 16);
}

__device__ __forceinline__ void glds16(const void* g, void* l) {
    __builtin_amdgcn_global_load_lds((gas_t*)g, (las_t*)l, 16, 0, 0);
}

// out-tensor offsets for direct writes
__device__ __forceinline__ size_t edge_out_off(int row) {    // row in [0,kBNE)
    int b = row / kNE, r = row - b * kNE;
    return ((size_t)(b * kG + kNN + r)) * kD;
}
__device__ __forceinline__ size_t node_out_off(int n) {      // n in [0,kBNN)
    int b = n / kNN, g = n - b * kNN;
    return ((size_t)(b * kG + g)) * kD;
}

// ---------------------------------------------------------------------------
// prep kernel: block < kB*kG -> fused embedding gather + ragged mean pool;
// block >= kB*kG -> W [K][N] fp32 -> Wt in MFMA-FRAGMENT-LINEAR bf16 layout:
//   frag (nf,kf): lane l holds W[k = kf*32 + (l>>4)*8 + m][n = nf*16 + (l&15)],
//   1KB per fragment at offset ((nf*32)+kf)*1024 + l*16. Layout verified by
//   r14's passing run (absmax 4.9e-4).
__global__ __launch_bounds__(256) void prep_kernel(const int* __restrict__ tokens,
                                                   const int* __restrict__ gids,
                                                   const float* __restrict__ emb,
                                                   float* __restrict__ nodes,
                                                   float* __restrict__ edges,
                                                   const float* __restrict__ Wm,
                                                   const float* __restrict__ Wu,
                                                   const float* __restrict__ We,
                                                   unsigned short* __restrict__ Wt) {
    __shared__ float tbuf[32][33];
    int bx = blockIdx.x;
    if (bx < kB * kG) {
        int b = bx >> 10, g = bx & (kG - 1);
        int d = threadIdx.x * 4;
        const int* row = gids + (size_t)b * kT;
        int lo = 0, hi = kT;
        while (lo < hi) { int m = (lo + hi) >> 1; if (row[m] < g) lo = m + 1; else hi = m; }
        int s = lo; hi = kT;
        while (lo < hi) { int m = (lo + hi) >> 1; if (row[m] <= g) lo = m + 1; else hi = m; }
        int e = lo;
        float4 acc = make_float4(0.f, 0.f, 0.f, 0.f);
        for (int t = s; t < e; ++t) {
            int tok = tokens[(size_t)b * kT + t];
            const float4 v = *(const float4*)(emb + (size_t)tok * kD + d);
            acc.x += v.x; acc.y += v.y; acc.z += v.z; acc.w += v.w;
        }
        int c = e - s;
        float sc = 1.0f / (float)(c > 0 ? c : 1);
        acc.x *= sc; acc.y *= sc; acc.z *= sc; acc.w *= sc;
        float* dstp = (g < kNN)
            ? (nodes + (size_t)(b * kNN + g) * kD + d)
            : (edges + (size_t)(b * kNE + (g - kNN)) * kD + d);
        *(float4*)dstp = acc;
    } else {
        int idx = bx - kB * kG;             // [0, 6*1024)
        int z = idx >> 10;
        int rem = idx & 1023;
        int n0 = (rem & 31) * 32, k0 = (rem >> 5) * 32;
        const float* W = (z < 2) ? (Wm + (size_t)z * kD * kD)
                       : (z < 4) ? (Wu + (size_t)(z - 2) * kD * kD)
                                 : (We + (size_t)(z - 4) * kD * kD);
        int r = threadIdx.x >> 3, c4 = (threadIdx.x & 7) * 4;
        const float4 v = *(const float4*)(W + (size_t)(k0 + r) * kD + n0 + c4);
        tbuf[r][c4] = v.x; tbuf[r][c4 + 1] = v.y; tbuf[r][c4 + 2] = v.z; tbuf[r][c4 + 3] = v.w;
        __syncthreads();
        if (threadIdx.x < 128) {
            int f = threadIdx.x >> 6, l = threadIdx.x & 63;
            alignas(16) unsigned short tmp[8];
#pragma unroll
            for (int m = 0; m < 8; ++m)
                tmp[m] = f2bf(tbuf[(l >> 4) * 8 + m][f * 16 + (l & 15)]);
            int nf = (rem & 31) * 2 + f;    // n0/16 + f
            int kf = rem >> 5;              // k0/32
            char* dst = (char*)Wt + (size_t)z * 2097152
                      + ((size_t)nf * 32 + kf) * 1024 + (size_t)l * 16;
            *(float4*)dst = *(const float4*)tmp;
        }
    }
}

// ---------------------------------------------------------------------------
// gather (+ optional node->out copy folded in, for L1)
template <int COPY>
__global__ void gather_kernel(const float* __restrict__ nodes,
                              const float* __restrict__ edges,
                              const int* __restrict__ src,
                              const int* __restrict__ dst,
                              unsigned short* __restrict__ bufM,
                              unsigned short* __restrict__ bufE,
                              float* __restrict__ out) {
    int d = threadIdx.x * 4;
    int e = blockIdx.x;
    if (COPY && e >= kBNE) {
        int n = e - kBNE;
        *(float4*)(out + node_out_off(n) + d) =
            *(const float4*)(nodes + (size_t)n * kD + d);
        return;
    }
    int s = src[e], t = dst[e];
    const float4 a = *(const float4*)(nodes + (size_t)s * kD + d);
    const float4 b = *(const float4*)(edges + (size_t)e * kD + d);
    const float4 c = *(const float4*)(nodes + (size_t)t * kD + d);
    ushort4 om, oe;
    om.x = f2bf(a.x + b.x); om.y = f2bf(a.y + b.y);
    om.z = f2bf(a.z + b.z); om.w = f2bf(a.w + b.w);
    oe.x = f2bf(a.x + c.x); oe.y = f2bf(a.y + c.y);
    oe.z = f2bf(a.z + c.z); oe.w = f2bf(a.w + c.w);
    *(ushort4*)(bufM + (size_t)e * kD + d) = om;
    *(ushort4*)(bufE + (size_t)e * kD + d) = oe;
}

// ---------------------------------------------------------------------------
// bf16 MFMA GEMM core. A [M][1024] bf16; Wtf = fragment-linear weights.
// 64x128 tile, BK=64, 4 waves (2x2 over 32x64 sub-tiles), 16x16x32 MFMA.
// A: LDS double-buffer (8KB/buf), XOR chunk layout, 2 glds/thread/stage.
// B: NO LDS — per-wave coalesced 1KB global loads of pre-packed fragments into
//    registers, one K-step ahead (ping-pong bfr[2], compile-time ph).
// Sync: plain r6-style __syncthreads() per step (drains vmcnt0+lgkm0) — B(t+1)
// regs and A(t+1) LDS are unconditionally valid at step t+1; no ordering
// assumptions, no fences (r14's fence scaffolding cost more than it saved).
// LDS reads/step drop 48KB -> 16KB; B rides the VMEM/L2 pipe concurrently.
// MODE 0: Cb[row][col] = bf16(relu(acc))                     (msg GEMM)
// MODE 1: Cf[row][col] += acc          (edge GEMM L0; unique rows)
// MODE 2: Of[edge_out_off(row)+col] = Ef[row][col] + acc     (edge GEMM L1)
// MODE 3: atomicAdd(Cf[idxp[row]][col], acc)                 (update L0)
// MODE 4: atomicAdd(Of[node_out_off(idxp[row])+col], acc)    (update L1)
template <int MODE>
__device__ __forceinline__ void gemm_body(const unsigned short* __restrict__ A,
                                          const unsigned short* __restrict__ Wtf,
                                          float* __restrict__ Cf,
                                          unsigned short* __restrict__ Cb,
                                          const float* __restrict__ Ef,
                                          const int* __restrict__ idxp,
                                          char* smem, int bn, int bm) {
    const int tid = threadIdx.x;
    const int lane = tid & 63;
    const int w = tid >> 6;
    const int wr = w >> 1, wc = w & 1;
    const int row0 = bm * 64, col0 = bn * 128;
    const int l15 = lane & 15, kg = lane >> 4;

    // ---- A staging: lane l covers slab-row (l>>3), chunk-pos (l&7);
    // source chunk = (l&7) ^ (l>>3)  (XOR layout, bank-conflict-free reads).
    const int sl8 = lane >> 3;
    const int sc  = (lane & 7) ^ sl8;
    const unsigned short* agp[2];
#pragma unroll
    for (int q = 0; q < 2; ++q)
        agp[q] = A + (size_t)(row0 + (w * 2 + q) * 8 + sl8) * kD + sc * 8;
    auto stage = [&](int bsel, int k0) {
        char* base = smem + bsel * 8192;
#pragma unroll
        for (int q = 0; q < 2; ++q)
            glds16(agp[q] + k0, base + (w * 2 + q) * 1024);
    };

    // ---- B fragment pointers: this wave reads frags nf = bn*8 + wc*4 + j.
    const char* bfrag[4];
#pragma unroll
    for (int j = 0; j < 4; ++j)
        bfrag[j] = (const char*)Wtf
                 + ((size_t)(bn * 8 + wc * 4 + j) * 32) * 1024 + (size_t)lane * 16;

    constexpr int nt = kD / 64;                 // 16 (even)
    bf16x8 bfr[2][2][4];                        // [ping][kk][j]

    stage(0, 0);
#pragma unroll
    for (int kk = 0; kk < 2; ++kk)
#pragma unroll
        for (int j = 0; j < 4; ++j)
            bfr[0][kk][j] = *(const bf16x8*)(bfrag[j] + (size_t)kk * 1024);
    __syncthreads();                            // buf0 + B(0) regs valid

    f32x4 acc[2][4] = {};
    for (int tt = 0; tt < nt; tt += 2) {
#pragma unroll
        for (int ph = 0; ph < 2; ++ph) {        // ph compile-time after unroll
            const int t = tt + ph;
            char* bufc = smem + (t & 1) * 8192;
            if (t + 1 < nt) {
                stage((t + 1) & 1, (t + 1) * 64);       // next A tile (glds)
#pragma unroll
                for (int kk = 0; kk < 2; ++kk)          // next B frags (regs)
#pragma unroll
                    for (int j = 0; j < 4; ++j)
                        bfr[ph ^ 1][kk][j] = *(const bf16x8*)(
                            bfrag[j] + (size_t)((t + 1) * 2 + kk) * 1024);
            }
            bf16x8 af[2][2];
#pragma unroll
            for (int kk = 0; kk < 2; ++kk)
#pragma unroll
                for (int i = 0; i < 2; ++i) {
                    int ar = wr * 32 + i * 16 + l15;
                    int p = ((kk << 2) | kg) ^ (ar & 7);
                    af[kk][i] = *(const bf16x8*)(bufc + ar * 128 + p * 16);
                }
            asm volatile("s_waitcnt lgkmcnt(0)" ::: "memory");  // af landed
#pragma unroll
            for (int kk = 0; kk < 2; ++kk)
#pragma unroll
                for (int i = 0; i < 2; ++i)
#pragma unroll
                    for (int j = 0; j < 4; ++j)
                        acc[i][j] = __builtin_amdgcn_mfma_f32_16x16x32_bf16(
                            af[kk][i], bfr[ph][kk][j], acc[i][j], 0, 0, 0);
            __syncthreads();                    // drain stage+loadB; wave sync
        }
    }

    // epilogue: C/D layout col=lane&15, row=(lane>>4)*4+reg
    const int lr = (lane >> 4) * 4;
#pragma unroll
    for (int i = 0; i < 2; ++i) {
        int rbase = row0 + wr * 32 + i * 16 + lr;
#pragma unroll
        for (int r = 0; r < 4; ++r) {
            int row = rbase + r;
            if (MODE == 0) {
                unsigned short* cp = Cb + (size_t)row * kD;
#pragma unroll
                for (int j = 0; j < 4; ++j) {
                    int col = col0 + wc * 64 + j * 16 + l15;
                    cp[col] = f2bf(fmaxf(acc[i][j][r], 0.f));
                }
            } else if (MODE == 1) {
                float* cp = Cf + (size_t)row * kD;
#pragma unroll
                for (int j = 0; j < 4; ++j) {
                    int col = col0 + wc * 64 + j * 16 + l15;
                    cp[col] += acc[i][j][r];
                }
            } else if (MODE == 2) {
                const float* ep = Ef + (size_t)row * kD;
                float* op = Cf + edge_out_off(row);
#pragma unroll
                for (int j = 0; j < 4; ++j) {
                    int col = col0 + wc * 64 + j * 16 + l15;
                    op[col] = ep[col] + acc[i][j][r];
                }
            } else if (MODE == 3) {
                float* cp = Cf + (size_t)idxp[row] * kD;
#pragma unroll
                for (int j = 0; j < 4; ++j) {
                    int col = col0 + wc * 64 + j * 16 + l15;
                    atomicAdd(cp + col, acc[i][j][r]);
                }
            } else {
                float* cp = Cf + node_out_off(idxp[row]);
#pragma unroll
                for (int j = 0; j < 4; ++j) {
                    int col = col0 + wc * 64 + j * 16 + l15;
                    atomicAdd(cp + col, acc[i][j][r]);
                }
            }
        }
    }
}

// L0: z=0 msgb = bf16(relu(bufM @ WtM^T));  z=1 edges += bufE @ WtE^T
__global__ __launch_bounds__(256) void gemm_dual_l0(const unsigned short* __restrict__ A0,
                                                    const unsigned short* __restrict__ B0,
                                                    unsigned short* __restrict__ C0,
                                                    const unsigned short* __restrict__ A1,
                                                    const unsigned short* __restrict__ B1,
                                                    float* __restrict__ C1) {
    __shared__ char smem[16384];
    if (blockIdx.z == 0)
        gemm_body<0>(A0, B0, nullptr, C0, nullptr, nullptr, smem, blockIdx.x, blockIdx.y);
    else
        gemm_body<1>(A1, B1, C1, nullptr, nullptr, nullptr, smem, blockIdx.x, blockIdx.y);
}

// L1: z=0 msgb = bf16(relu(bufM @ WtM^T));  z=1 out_edges = edges + bufE @ WtE^T
__global__ __launch_bounds__(256) void gemm_dual_l1(const unsigned short* __restrict__ A0,
                                                    const unsigned short* __restrict__ B0,
                                                    unsigned short* __restrict__ C0,
                                                    const unsigned short* __restrict__ A1,
                                                    const unsigned short* __restrict__ B1,
                                                    float* __restrict__ outp,
                                                    const float* __restrict__ edges) {
    __shared__ char smem[16384];
    if (blockIdx.z == 0)
        gemm_body<0>(A0, B0, nullptr, C0, nullptr, nullptr, smem, blockIdx.x, blockIdx.y);
    else
        gemm_body<2>(A1, B1, outp, nullptr, edges, nullptr, smem, blockIdx.x, blockIdx.y);
}

// nodes[dst[row]] += (msgb @ WtU^T)[row]   (full K, one atomic per element)
__global__ __launch_bounds__(256) void gemm_upd_l0(const unsigned short* __restrict__ A,
                                                   const unsigned short* __restrict__ B,
                                                   float* __restrict__ C,
                                                   const int* __restrict__ dstIdx) {
    __shared__ char smem[16384];
    gemm_body<3>(A, B, C, nullptr, nullptr, dstIdx, smem, blockIdx.x, blockIdx.y);
}

// out_nodes[dst[row]] += (msgb @ WtU^T)[row]  (final layer -> d_out directly)
__global__ __launch_bounds__(256) void gemm_upd_l1(const unsigned short* __restrict__ A,
                                                   const unsigned short* __restrict__ B,
                                                   float* __restrict__ outp,
                                                   const int* __restrict__ dstIdx) {
    __shared__ char smem[16384];
    gemm_body<4>(A, B, outp, nullptr, nullptr, dstIdx, smem, blockIdx.x, blockIdx.y);
}

// ---------------------------------------------------------------------------
extern "C" void kernel_launch(void* const* d_in, const int* in_sizes, int n_in,
                              void* d_out, int out_size, void* d_ws, size_t ws_size,
                              hipStream_t stream) {
    const int*   tokens = (const int*)d_in[0];
    const int*   gids   = (const int*)d_in[1];
    const int*   eidx   = (const int*)d_in[3];
    const float* emb    = (const float*)d_in[4];
    const float* Wm     = (const float*)d_in[5];
    const float* Wu     = (const float*)d_in[6];
    const float* We     = (const float*)d_in[7];
    float* out = (float*)d_out;

    // workspace layout
    constexpr size_t szNodes = (size_t)kBNN * kD * 4;   // fp32 master
    constexpr size_t szEdges = (size_t)kBNE * kD * 4;   // fp32 master
    constexpr size_t szBufM  = (size_t)kBNE * kD * 2;   // bf16
    constexpr size_t szBufE  = (size_t)kBNE * kD * 2;   // bf16
    constexpr size_t szMsgB  = (size_t)kBNE * kD * 2;   // bf16
    char* ws = (char*)d_ws;
    float*          nodes = (float*)ws;
    float*          edges = (float*)(ws + szNodes);
    unsigned short* bufM  = (unsigned short*)(ws + szNodes + szEdges);
    unsigned short* bufE  = (unsigned short*)(ws + szNodes + szEdges + szBufM);
    unsigned short* msgb  = (unsigned short*)(ws + szNodes + szEdges + szBufM + szBufE);
    unsigned short* Wt    = (unsigned short*)(ws + szNodes + szEdges + szBufM + szBufE + szMsgB);

    const int* srcIdx = eidx;
    const int* dstIdx = eidx + kBNE;
    unsigned short* WtM = Wt;                           // frag-linear, 2MB each
    unsigned short* WtU = Wt + (size_t)2 * kD * kD;
    unsigned short* WtE = Wt + (size_t)4 * kD * kD;

    // pool (binary-search bounds) + weight frag-pack, one launch
    prep_kernel<<<kB * kG + 6 * 1024, 256, 0, stream>>>(
        tokens, gids, emb, nodes, edges, Wm, Wu, We, Wt);

    constexpr int mt = kBNE / 64;                // 53
    const dim3 gdual(kD / 128, mt, 2);           // 848 blocks
    const dim3 gupd(kD / 128, mt, 1);            // 424 blocks, full K

    // ---- layer 0 ----
    gather_kernel<0><<<kBNE, 256, 0, stream>>>(nodes, edges, srcIdx, dstIdx, bufM, bufE, out);
    gemm_dual_l0<<<gdual, 256, 0, stream>>>(bufM, WtM, msgb, bufE, WtE, edges);
    gemm_upd_l0<<<gupd, 256, 0, stream>>>(msgb, WtU, nodes, dstIdx);

    // ---- layer 1 (writes final values straight into d_out) ----
    gather_kernel<1><<<kBNE + kBNN, 256, 0, stream>>>(nodes, edges, srcIdx, dstIdx, bufM, bufE, out);
    gemm_dual_l1<<<gdual, 256, 0, stream>>>(bufM, WtM + (size_t)kD * kD, msgb,
                                            bufE, WtE + (size_t)kD * kD, out, edges);
    gemm_upd_l1<<<gupd, 256, 0, stream>>>(msgb, WtU + (size_t)kD * kD, out, dstIdx);
}

// Round 16
// 139.663 us; speedup vs baseline: 1.1934x; 1.1809x over previous
//
#include <hip/hip_runtime.h>

// Problem constants
constexpr int kB  = 8;
constexpr int kT  = 2048;
constexpr int kG  = 1024;
constexpr int kNN = 600;
constexpr int kNE = 424;
constexpr int kD  = 1024;
constexpr int kL  = 2;
constexpr int kBNN = kB * kNN;   // 4800
constexpr int kBNE = kB * kNE;   // 3392
static_assert(kBNE % 64 == 0, "M tiles exact");

typedef __attribute__((ext_vector_type(4))) float f32x4;
typedef __attribute__((ext_vector_type(8))) short bf16x8;
typedef __attribute__((address_space(1))) const void gas_t;
typedef __attribute__((address_space(3))) void las_t;

__device__ __forceinline__ unsigned short f2bf(float x) {
    union { float f; unsigned u; } v; v.f = x;
    unsigned r = v.u + 0x7FFF + ((v.u >> 16) & 1);
    return (unsigned short)(r >> 16);
}

__device__ __forceinline__ void glds16(const void* g, void* l) {
    __builtin_amdgcn_global_load_lds((gas_t*)g, (las_t*)l, 16, 0, 0);
}

// out-tensor offsets for direct writes
__device__ __forceinline__ size_t edge_out_off(int row) {    // row in [0,kBNE)
    int b = row / kNE, r = row - b * kNE;
    return ((size_t)(b * kG + kNN + r)) * kD;
}
__device__ __forceinline__ size_t node_out_off(int n) {      // n in [0,kBNN)
    int b = n / kNN, g = n - b * kNN;
    return ((size_t)(b * kG + g)) * kD;
}

// XCD-aware tile swizzle (T1): dispatch XCD = flat%8 (424 % 8 == 0), so the
// default map puts the SAME bn on each XCD -> every XCD streams all A panels
// (~14MB) through its 4MB L2. Remap (bijective on [0,424)) so each XCD gets a
// CONTIGUOUS bm chunk (~1.7MB of A) -> A stays L2-resident per XCD.
__device__ __forceinline__ void swz_tile(int bx, int by, int& bn, int& bm) {
    int f = bx + 8 * by;            // [0, 424)
    int xcd = f & 7, i = f >> 3;    // i in [0, 53)
    int nf = xcd * 53 + i;          // per-XCD contiguous range
    bm = nf >> 3;                   // contiguous bm per XCD
    bn = nf & 7;
}

// ---------------------------------------------------------------------------
// prep kernel: block < kB*kG -> fused embedding gather + ragged mean pool
//              (bounds via binary search over the sorted group-id row);
//              block >= kB*kG -> W [K][N] fp32 -> Wt [N][K] bf16 transpose.
__global__ __launch_bounds__(256) void prep_kernel(const int* __restrict__ tokens,
                                                   const int* __restrict__ gids,
                                                   const float* __restrict__ emb,
                                                   float* __restrict__ nodes,
                                                   float* __restrict__ edges,
                                                   const float* __restrict__ Wm,
                                                   const float* __restrict__ Wu,
                                                   const float* __restrict__ We,
                                                   unsigned short* __restrict__ Wt) {
    __shared__ float tbuf[32][33];
    int bx = blockIdx.x;
    if (bx < kB * kG) {
        int b = bx >> 10, g = bx & (kG - 1);
        int d = threadIdx.x * 4;
        const int* row = gids + (size_t)b * kT;
        int lo = 0, hi = kT;
        while (lo < hi) { int m = (lo + hi) >> 1; if (row[m] < g) lo = m + 1; else hi = m; }
        int s = lo; hi = kT;
        while (lo < hi) { int m = (lo + hi) >> 1; if (row[m] <= g) lo = m + 1; else hi = m; }
        int e = lo;
        float4 acc = make_float4(0.f, 0.f, 0.f, 0.f);
        for (int t = s; t < e; ++t) {
            int tok = tokens[(size_t)b * kT + t];
            const float4 v = *(const float4*)(emb + (size_t)tok * kD + d);
            acc.x += v.x; acc.y += v.y; acc.z += v.z; acc.w += v.w;
        }
        int c = e - s;
        float sc = 1.0f / (float)(c > 0 ? c : 1);
        acc.x *= sc; acc.y *= sc; acc.z *= sc; acc.w *= sc;
        float* dstp = (g < kNN)
            ? (nodes + (size_t)(b * kNN + g) * kD + d)
            : (edges + (size_t)(b * kNE + (g - kNN)) * kD + d);
        *(float4*)dstp = acc;
    } else {
        int idx = bx - kB * kG;             // [0, 6*1024)
        int z = idx >> 10;
        int rem = idx & 1023;
        int n0 = (rem & 31) * 32, k0 = (rem >> 5) * 32;
        const float* W = (z < 2) ? (Wm + (size_t)z * kD * kD)
                       : (z < 4) ? (Wu + (size_t)(z - 2) * kD * kD)
                                 : (We + (size_t)(z - 4) * kD * kD);
        unsigned short* outp = Wt + (size_t)z * kD * kD;
        int r = threadIdx.x >> 3, c4 = (threadIdx.x & 7) * 4;
        const float4 v = *(const float4*)(W + (size_t)(k0 + r) * kD + n0 + c4);
        tbuf[r][c4] = v.x; tbuf[r][c4 + 1] = v.y; tbuf[r][c4 + 2] = v.z; tbuf[r][c4 + 3] = v.w;
        __syncthreads();
        ushort4 o;
        o.x = f2bf(tbuf[c4 + 0][r]); o.y = f2bf(tbuf[c4 + 1][r]);
        o.z = f2bf(tbuf[c4 + 2][r]); o.w = f2bf(tbuf[c4 + 3][r]);
        *(ushort4*)(outp + (size_t)(n0 + r) * kD + k0 + c4) = o;
    }
}

// ---------------------------------------------------------------------------
// gather (+ optional node->out copy folded in, for L1)
template <int COPY>
__global__ void gather_kernel(const float* __restrict__ nodes,
                              const float* __restrict__ edges,
                              const int* __restrict__ src,
                              const int* __restrict__ dst,
                              unsigned short* __restrict__ bufM,
                              unsigned short* __restrict__ bufE,
                              float* __restrict__ out) {
    int d = threadIdx.x * 4;
    int e = blockIdx.x;
    if (COPY && e >= kBNE) {
        int n = e - kBNE;
        *(float4*)(out + node_out_off(n) + d) =
            *(const float4*)(nodes + (size_t)n * kD + d);
        return;
    }
    int s = src[e], t = dst[e];
    const float4 a = *(const float4*)(nodes + (size_t)s * kD + d);
    const float4 b = *(const float4*)(edges + (size_t)e * kD + d);
    const float4 c = *(const float4*)(nodes + (size_t)t * kD + d);
    ushort4 om, oe;
    om.x = f2bf(a.x + b.x); om.y = f2bf(a.y + b.y);
    om.z = f2bf(a.z + b.z); om.w = f2bf(a.w + b.w);
    oe.x = f2bf(a.x + c.x); oe.y = f2bf(a.y + c.y);
    oe.z = f2bf(a.z + c.z); oe.w = f2bf(a.w + c.w);
    *(ushort4*)(bufM + (size_t)e * kD + d) = om;
    *(ushort4*)(bufE + (size_t)e * kD + d) = oe;
}

// ---------------------------------------------------------------------------
// bf16 MFMA GEMM core. A [M][1024] bf16, Wt [N][K] bf16 (B^T layout).
// 64x128 tile, BK=64, 4 waves (2x2 over 32x64 sub-tiles), 16x16x32 MFMA.
// 3-buffer ring, counted vmcnt, ONE barrier per K-step (r12 structure, the
// verified-best 147.1us schedule):
//   [vmcnt(6)][bar][stage(t+2 -> buf[(t+2)%3])][ds_read][lgkm0][MFMA]
// Safety: buf[(t+2)%3] == buf[(t-1)%3]; every wave drains its reads of that
// buffer with lgkmcnt(0) before reaching bar(t). LDS 3x24KB = 72KB.
// LDS layout per buffer: A [64 rows][8 chunks][16B] (8KB) + B [128][8][16B]
// (16KB); chunk position p holds source k-chunk p ^ (row&7) -> fragment
// reads are bank-conflict-free while staging stays 128B-contiguous per row.
// MODE 0: Cb[row][col] = bf16(relu(acc))                     (msg GEMM)
// MODE 1: Cf[row][col] += acc          (edge GEMM L0; unique rows)
// MODE 2: Of[edge_out_off(row)+col] = Ef[row][col] + acc     (edge GEMM L1)
// MODE 3: atomicAdd(Cf[idxp[row]][col], acc)                 (update L0)
// MODE 4: atomicAdd(Of[node_out_off(idxp[row])+col], acc)    (update L1)
template <int MODE>
__device__ __forceinline__ void gemm_body(const unsigned short* __restrict__ A,
                                          const unsigned short* __restrict__ Wt,
                                          float* __restrict__ Cf,
                                          unsigned short* __restrict__ Cb,
                                          const float* __restrict__ Ef,
                                          const int* __restrict__ idxp,
                                          char* smem, int bn, int bm) {
    const int tid = threadIdx.x;
    const int lane = tid & 63;
    const int w = tid >> 6;
    const int wr = w >> 1, wc = w & 1;
    const int row0 = bm * 64, col0 = bn * 128;
    const int l15 = lane & 15, kg = lane >> 4;

    // staging: lane l covers slab-row (l>>3), chunk-position (l&7) of each
    // 8-row slab; source chunk = (l&7) ^ (l>>3) implements the XOR layout.
    const int sl8 = lane >> 3;                 // 0..7
    const int sc  = (lane & 7) ^ sl8;          // source k-chunk (16B units)
    const unsigned short* agp[2];
    const unsigned short* bgp[4];
#pragma unroll
    for (int q = 0; q < 2; ++q)
        agp[q] = A + (size_t)(row0 + (w * 2 + q) * 8 + sl8) * kD + sc * 8;
#pragma unroll
    for (int q = 0; q < 4; ++q)
        bgp[q] = Wt + (size_t)(col0 + (w * 4 + q) * 8 + sl8) * kD + sc * 8;
    auto stage = [&](int bsel, int k0) {
        char* base = smem + bsel * 24576;
#pragma unroll
        for (int q = 0; q < 2; ++q)
            glds16(agp[q] + k0, base + (w * 2 + q) * 1024);          // A slabs
#pragma unroll
        for (int q = 0; q < 4; ++q)
            glds16(bgp[q] + k0, base + 8192 + (w * 4 + q) * 1024);   // B slabs
    };

    constexpr int nt = kD / 64;                 // 16
    stage(0, 0);
    stage(1, 64);

    f32x4 acc[2][4] = {};
    int cur = 0;
    for (int t = 0; t < nt; ++t) {
        char* bufc = smem + cur * 24576;
        if (t < nt - 1) asm volatile("s_waitcnt vmcnt(6)" ::: "memory");
        else            asm volatile("s_waitcnt vmcnt(0)" ::: "memory");
        __builtin_amdgcn_s_barrier();           // buf[cur] staged; all reads of
                                                // buf[(cur+2)%3] drained (lgkm0)
        if (t + 2 < nt) stage((cur + 2) % 3, (t + 2) * 64);
        bf16x8 af[2][2], bf[2][4];
#pragma unroll
        for (int kk = 0; kk < 2; ++kk) {
#pragma unroll
            for (int i = 0; i < 2; ++i) {
                int ar = wr * 32 + i * 16 + l15;
                int p = ((kk << 2) | kg) ^ (ar & 7);
                af[kk][i] = *(const bf16x8*)(bufc + ar * 128 + p * 16);
            }
#pragma unroll
            for (int j = 0; j < 4; ++j) {
                int br = wc * 64 + j * 16 + l15;
                int p = ((kk << 2) | kg) ^ (br & 7);
                bf[kk][j] = *(const bf16x8*)(bufc + 8192 + br * 128 + p * 16);
            }
        }
        asm volatile("s_waitcnt lgkmcnt(0)" ::: "memory");  // my reads drained
#pragma unroll
        for (int kk = 0; kk < 2; ++kk)
#pragma unroll
            for (int i = 0; i < 2; ++i)
#pragma unroll
                for (int j = 0; j < 4; ++j)
                    acc[i][j] = __builtin_amdgcn_mfma_f32_16x16x32_bf16(
                        af[kk][i], bf[kk][j], acc[i][j], 0, 0, 0);
        cur = (cur == 2) ? 0 : cur + 1;
    }
    // epilogue: C/D layout col=lane&15, row=(lane>>4)*4+reg
    const int lr = (lane >> 4) * 4;
#pragma unroll
    for (int i = 0; i < 2; ++i) {
        int rbase = row0 + wr * 32 + i * 16 + lr;
#pragma unroll
        for (int r = 0; r < 4; ++r) {
            int row = rbase + r;
            if (MODE == 0) {
                unsigned short* cp = Cb + (size_t)row * kD;
#pragma unroll
                for (int j = 0; j < 4; ++j) {
                    int col = col0 + wc * 64 + j * 16 + l15;
                    cp[col] = f2bf(fmaxf(acc[i][j][r], 0.f));
                }
            } else if (MODE == 1) {
                float* cp = Cf + (size_t)row * kD;
#pragma unroll
                for (int j = 0; j < 4; ++j) {
                    int col = col0 + wc * 64 + j * 16 + l15;
                    cp[col] += acc[i][j][r];
                }
            } else if (MODE == 2) {
                const float* ep = Ef + (size_t)row * kD;
                float* op = Cf + edge_out_off(row);
#pragma unroll
                for (int j = 0; j < 4; ++j) {
                    int col = col0 + wc * 64 + j * 16 + l15;
                    op[col] = ep[col] + acc[i][j][r];
                }
            } else if (MODE == 3) {
                float* cp = Cf + (size_t)idxp[row] * kD;
#pragma unroll
                for (int j = 0; j < 4; ++j) {
                    int col = col0 + wc * 64 + j * 16 + l15;
                    atomicAdd(cp + col, acc[i][j][r]);
                }
            } else {
                float* cp = Cf + node_out_off(idxp[row]);
#pragma unroll
                for (int j = 0; j < 4; ++j) {
                    int col = col0 + wc * 64 + j * 16 + l15;
                    atomicAdd(cp + col, acc[i][j][r]);
                }
            }
        }
    }
}

// L0: z=0 msgb = bf16(relu(bufM @ WtM^T));  z=1 edges += bufE @ WtE^T
__global__ __launch_bounds__(256) void gemm_dual_l0(const unsigned short* __restrict__ A0,
                                                    const unsigned short* __restrict__ B0,
                                                    unsigned short* __restrict__ C0,
                                                    const unsigned short* __restrict__ A1,
                                                    const unsigned short* __restrict__ B1,
                                                    float* __restrict__ C1) {
    __shared__ char smem[73728];
    int bn, bm; swz_tile(blockIdx.x, blockIdx.y, bn, bm);
    if (blockIdx.z == 0)
        gemm_body<0>(A0, B0, nullptr, C0, nullptr, nullptr, smem, bn, bm);
    else
        gemm_body<1>(A1, B1, C1, nullptr, nullptr, nullptr, smem, bn, bm);
}

// L1: z=0 msgb = bf16(relu(bufM @ WtM^T));  z=1 out_edges = edges + bufE @ WtE^T
__global__ __launch_bounds__(256) void gemm_dual_l1(const unsigned short* __restrict__ A0,
                                                    const unsigned short* __restrict__ B0,
                                                    unsigned short* __restrict__ C0,
                                                    const unsigned short* __restrict__ A1,
                                                    const unsigned short* __restrict__ B1,
                                                    float* __restrict__ outp,
                                                    const float* __restrict__ edges) {
    __shared__ char smem[73728];
    int bn, bm; swz_tile(blockIdx.x, blockIdx.y, bn, bm);
    if (blockIdx.z == 0)
        gemm_body<0>(A0, B0, nullptr, C0, nullptr, nullptr, smem, bn, bm);
    else
        gemm_body<2>(A1, B1, outp, nullptr, edges, nullptr, smem, bn, bm);
}

// nodes[dst[row]] += (msgb @ WtU^T)[row]   (full K, one atomic per element)
__global__ __launch_bounds__(256) void gemm_upd_l0(const unsigned short* __restrict__ A,
                                                   const unsigned short* __restrict__ B,
                                                   float* __restrict__ C,
                                                   const int* __restrict__ dstIdx) {
    __shared__ char smem[73728];
    int bn, bm; swz_tile(blockIdx.x, blockIdx.y, bn, bm);
    gemm_body<3>(A, B, C, nullptr, nullptr, dstIdx, smem, bn, bm);
}

// out_nodes[dst[row]] += (msgb @ WtU^T)[row]  (final layer -> d_out directly)
__global__ __launch_bounds__(256) void gemm_upd_l1(const unsigned short* __restrict__ A,
                                                   const unsigned short* __restrict__ B,
                                                   float* __restrict__ outp,
                                                   const int* __restrict__ dstIdx) {
    __shared__ char smem[73728];
    int bn, bm; swz_tile(blockIdx.x, blockIdx.y, bn, bm);
    gemm_body<4>(A, B, outp, nullptr, nullptr, dstIdx, smem, bn, bm);
}

// ---------------------------------------------------------------------------
extern "C" void kernel_launch(void* const* d_in, const int* in_sizes, int n_in,
                              void* d_out, int out_size, void* d_ws, size_t ws_size,
                              hipStream_t stream) {
    const int*   tokens = (const int*)d_in[0];
    const int*   gids   = (const int*)d_in[1];
    const int*   eidx   = (const int*)d_in[3];
    const float* emb    = (const float*)d_in[4];
    const float* Wm     = (const float*)d_in[5];
    const float* Wu     = (const float*)d_in[6];
    const float* We     = (const float*)d_in[7];
    float* out = (float*)d_out;

    // workspace layout
    constexpr size_t szNodes = (size_t)kBNN * kD * 4;   // fp32 master
    constexpr size_t szEdges = (size_t)kBNE * kD * 4;   // fp32 master
    constexpr size_t szBufM  = (size_t)kBNE * kD * 2;   // bf16
    constexpr size_t szBufE  = (size_t)kBNE * kD * 2;   // bf16
    constexpr size_t szMsgB  = (size_t)kBNE * kD * 2;   // bf16
    char* ws = (char*)d_ws;
    float*          nodes = (float*)ws;
    float*          edges = (float*)(ws + szNodes);
    unsigned short* bufM  = (unsigned short*)(ws + szNodes + szEdges);
    unsigned short* bufE  = (unsigned short*)(ws + szNodes + szEdges + szBufM);
    unsigned short* msgb  = (unsigned short*)(ws + szNodes + szEdges + szBufM + szBufE);
    unsigned short* Wt    = (unsigned short*)(ws + szNodes + szEdges + szBufM + szBufE + szMsgB);

    const int* srcIdx = eidx;
    const int* dstIdx = eidx + kBNE;
    unsigned short* WtM = Wt;                           // [l][N][K]
    unsigned short* WtU = Wt + (size_t)2 * kD * kD;
    unsigned short* WtE = Wt + (size_t)4 * kD * kD;

    // pool (binary-search bounds) + weight transpose, one launch
    prep_kernel<<<kB * kG + 6 * 1024, 256, 0, stream>>>(
        tokens, gids, emb, nodes, edges, Wm, Wu, We, Wt);

    constexpr int mt = kBNE / 64;                // 53
    const dim3 gdual(kD / 128, mt, 2);           // 848 blocks
    const dim3 gupd(kD / 128, mt, 1);            // 424 blocks, full K

    // ---- layer 0 ----
    gather_kernel<0><<<kBNE, 256, 0, stream>>>(nodes, edges, srcIdx, dstIdx, bufM, bufE, out);
    gemm_dual_l0<<<gdual, 256, 0, stream>>>(bufM, WtM, msgb, bufE, WtE, edges);
    gemm_upd_l0<<<gupd, 256, 0, stream>>>(msgb, WtU, nodes, dstIdx);

    // ---- layer 1 (writes final values straight into d_out) ----
    gather_kernel<1><<<kBNE + kBNN, 256, 0, stream>>>(nodes, edges, srcIdx, dstIdx, bufM, bufE, out);
    gemm_dual_l1<<<gdual, 256, 0, stream>>>(bufM, WtM + (size_t)kD * kD, msgb,
                                            bufE, WtE + (size_t)kD * kD, out, edges);
    gemm_upd_l1<<<gupd, 256, 0, stream>>>(msgb, WtU + (size_t)kD * kD, out, dstIdx);
}